// Round 1
// baseline (221.344 us; speedup 1.0000x reference)
//
#include <hip/hip_runtime.h>
#include <hip/hip_bf16.h>
#include <math.h>

#define VOCAB 50257
#define VPAD  50304   // 393*128
#define DMODEL 128
#define BATCH 4096
#define NW 10         // 2*WINDOW

typedef __bf16 bf16_t;
typedef __bf16 bf16x4 __attribute__((ext_vector_type(4)));
typedef __bf16 bf16x8 __attribute__((ext_vector_type(8)));
typedef float  floatx4 __attribute__((ext_vector_type(4)));

// ---------------------------------------------------------------------------
// Kernel 1: cbow = mean of 10 context embeddings -> bf16; center logit (fp32);
//           zero-init sumexp accumulator. One block (128 threads) per row.
// ---------------------------------------------------------------------------
__global__ void k_cbow(const int* __restrict__ ctx, const int* __restrict__ center,
                       const float* __restrict__ emb, const float* __restrict__ W,
                       bf16_t* __restrict__ cbow_bf, float* __restrict__ center_logit,
                       float* __restrict__ sumexp) {
    const int b = blockIdx.x;
    const int d = threadIdx.x;  // 0..127
    const int* cr = ctx + b * NW;
    float s = 0.f;
#pragma unroll
    for (int w = 0; w < NW; ++w) {
        int id = cr[w];
        s += emb[(long)id * DMODEL + d];
    }
    s *= (1.0f / NW);
    cbow_bf[b * DMODEL + d] = (bf16_t)s;

    const int cid = center[b];
    float p = s * W[(long)cid * DMODEL + d];
    // reduce 128 threads (2 waves)
    p += __shfl_down(p, 32, 64);
    p += __shfl_down(p, 16, 64);
    p += __shfl_down(p, 8, 64);
    p += __shfl_down(p, 4, 64);
    p += __shfl_down(p, 2, 64);
    p += __shfl_down(p, 1, 64);
    __shared__ float red[2];
    if ((threadIdx.x & 63) == 0) red[threadIdx.x >> 6] = p;
    __syncthreads();
    if (threadIdx.x == 0) {
        center_logit[b] = red[0] + red[1];
        sumexp[b] = 0.f;   // zero-init accumulator for k_gemm
    }
}

// ---------------------------------------------------------------------------
// Kernel 2: W fp32 -> bf16, zero-padded to VPAD rows.
// ---------------------------------------------------------------------------
__global__ void k_wconv(const float* __restrict__ W, bf16_t* __restrict__ Wb) {
    long i4 = (long)blockIdx.x * blockDim.x + threadIdx.x;
    long base = i4 * 4;
    if (base >= (long)VPAD * DMODEL) return;
    float4 v;
    if (base < (long)VOCAB * DMODEL) {
        v = *reinterpret_cast<const float4*>(W + base);
    } else {
        v = make_float4(0.f, 0.f, 0.f, 0.f);
    }
    bf16x4 o;
    o[0] = (bf16_t)v.x; o[1] = (bf16_t)v.y; o[2] = (bf16_t)v.z; o[3] = (bf16_t)v.w;
    *reinterpret_cast<bf16x4*>(Wb + base) = o;
}

// ---------------------------------------------------------------------------
// Kernel 3: fused logits GEMM + exp + per-row sumexp atomic accumulation.
//   Block tile: BM=128 rows x BN=128 vocab cols, K=128 (full).
//   A (cbow) fragments -> registers (loaded once); B (W slab) -> LDS.
//   grid.x = BATCH/128 (m, fast-varying for L2 reuse of B slab), grid.y = VPAD/128.
// ---------------------------------------------------------------------------
#define BM 128
#define BN 128
#define LDB 136   // +8 bf16 pad: row stride 272 B -> 2-way bank aliasing (free)

__launch_bounds__(256)
__global__ void k_gemm(const bf16_t* __restrict__ A, const bf16_t* __restrict__ Wb,
                       float* __restrict__ sumexp) {
    __shared__ bf16_t Bs[BN * LDB];
    const int tid  = threadIdx.x;
    const int lane = tid & 63;
    const int wv   = tid >> 6;     // 0..3
    const int l15  = lane & 15;
    const int q    = lane >> 4;    // 0..3
    const int m0   = blockIdx.x * BM;
    const int n0   = blockIdx.y * BN;

    // Preload A fragments: wave wv covers rows m0 + wv*32 + {0,16} + l15.
    // A-frag layout (16x16x32): m = lane&15, k = (lane>>4)*8 + j  (8 contiguous bf16).
    bf16x8 afrag[2][4];
#pragma unroll
    for (int mf = 0; mf < 2; ++mf) {
        const int row = m0 + wv * 32 + mf * 16 + l15;
        const bf16_t* ap = A + (long)row * DMODEL + q * 8;
#pragma unroll
        for (int ks = 0; ks < 4; ++ks)
            afrag[mf][ks] = *reinterpret_cast<const bf16x8*>(ap + ks * 32);
    }

    // Stage B slab: 128 W-rows x 128 k, bf16. 256 threads x 8 iters x 16 B.
    {
        const bf16_t* src = Wb + (long)n0 * DMODEL;
#pragma unroll
        for (int i = 0; i < 8; ++i) {
            int linear = i * 256 + tid;          // 0..2047
            int row = linear >> 4;
            int col = (linear & 15) * 8;
            bf16x8 v = *reinterpret_cast<const bf16x8*>(src + row * DMODEL + col);
            *reinterpret_cast<bf16x8*>(&Bs[row * LDB + col]) = v;
        }
    }
    __syncthreads();

    floatx4 acc[2][8];
#pragma unroll
    for (int mf = 0; mf < 2; ++mf)
#pragma unroll
        for (int nf = 0; nf < 8; ++nf)
            acc[mf][nf] = (floatx4){0.f, 0.f, 0.f, 0.f};

    // B-frag layout: n = lane&15, k = (lane>>4)*8 + j -> 8 contiguous bf16 of W row n.
#pragma unroll
    for (int ks = 0; ks < 4; ++ks) {
#pragma unroll
        for (int nf = 0; nf < 8; ++nf) {
            bf16x8 bfrag = *reinterpret_cast<const bf16x8*>(
                &Bs[(nf * 16 + l15) * LDB + ks * 32 + q * 8]);
            acc[0][nf] = __builtin_amdgcn_mfma_f32_16x16x32_bf16(afrag[0][ks], bfrag, acc[0][nf], 0, 0, 0);
            acc[1][nf] = __builtin_amdgcn_mfma_f32_16x16x32_bf16(afrag[1][ks], bfrag, acc[1][nf], 0, 0, 0);
        }
    }

    // Epilogue: exp + reduce over the 128 cols of this slab, atomically merge per row.
    // C/D layout: col = lane&15, row = (lane>>4)*4 + reg.
#pragma unroll
    for (int mf = 0; mf < 2; ++mf) {
        float s0 = 0.f, s1 = 0.f, s2 = 0.f, s3 = 0.f;
#pragma unroll
        for (int nf = 0; nf < 8; ++nf) {
            const int col = n0 + nf * 16 + l15;
            const bool ok = (col < VOCAB);
            floatx4 a = acc[mf][nf];
            s0 += ok ? __expf(a[0]) : 0.f;
            s1 += ok ? __expf(a[1]) : 0.f;
            s2 += ok ? __expf(a[2]) : 0.f;
            s3 += ok ? __expf(a[3]) : 0.f;
        }
#pragma unroll
        for (int off = 1; off < 16; off <<= 1) {
            s0 += __shfl_xor(s0, off, 64);
            s1 += __shfl_xor(s1, off, 64);
            s2 += __shfl_xor(s2, off, 64);
            s3 += __shfl_xor(s3, off, 64);
        }
        if (l15 == 0) {
            const int rbase = m0 + wv * 32 + mf * 16 + q * 4;
            atomicAdd(&sumexp[rbase + 0], s0);
            atomicAdd(&sumexp[rbase + 1], s1);
            atomicAdd(&sumexp[rbase + 2], s2);
            atomicAdd(&sumexp[rbase + 3], s3);
        }
    }
}

// ---------------------------------------------------------------------------
// Kernel 4: loss = mean_b( log(sumexp[b]) - center_logit[b] ). One block.
// ---------------------------------------------------------------------------
__global__ void k_loss(const float* __restrict__ sumexp,
                       const float* __restrict__ center_logit,
                       float* __restrict__ out) {
    float acc = 0.f;
    for (int b = threadIdx.x; b < BATCH; b += 256)
        acc += logf(sumexp[b]) - center_logit[b];
    acc += __shfl_down(acc, 32, 64);
    acc += __shfl_down(acc, 16, 64);
    acc += __shfl_down(acc, 8, 64);
    acc += __shfl_down(acc, 4, 64);
    acc += __shfl_down(acc, 2, 64);
    acc += __shfl_down(acc, 1, 64);
    __shared__ float red[4];
    if ((threadIdx.x & 63) == 0) red[threadIdx.x >> 6] = acc;
    __syncthreads();
    if (threadIdx.x == 0)
        out[0] = (red[0] + red[1] + red[2] + red[3]) * (1.0f / BATCH);
}

// ---------------------------------------------------------------------------
extern "C" void kernel_launch(void* const* d_in, const int* in_sizes, int n_in,
                              void* d_out, int out_size, void* d_ws, size_t ws_size,
                              hipStream_t stream) {
    const int*   ctx    = (const int*)d_in[0];
    const int*   center = (const int*)d_in[1];
    const float* emb    = (const float*)d_in[2];
    const float* W      = (const float*)d_in[3];
    float*       out    = (float*)d_out;

    char* ws = (char*)d_ws;
    // layout: Wb (VPAD*128*2 = 12,877,824 B) | cbow (4096*128*2 = 1,048,576 B)
    //         | center_logit (16,384 B) | sumexp (16,384 B)   -> ~13.96 MB total
    bf16_t* Wb           = (bf16_t*)ws;
    bf16_t* cbow         = (bf16_t*)(ws + 12877824);
    float*  center_logit = (float*)(ws + 13926400);
    float*  sumexp       = (float*)(ws + 13942784);

    k_cbow<<<BATCH, 128, 0, stream>>>(ctx, center, emb, W, cbow, center_logit, sumexp);
    k_wconv<<<(VPAD * DMODEL / 4 + 255) / 256, 256, 0, stream>>>(W, Wb);
    dim3 g3(BATCH / BM, VPAD / BN);
    k_gemm<<<g3, 256, 0, stream>>>(cbow, Wb, sumexp);
    k_loss<<<1, 256, 0, stream>>>(sumexp, center_logit, out);
}

// Round 2
// 186.889 us; speedup vs baseline: 1.1844x; 1.1844x over previous
//
#include <hip/hip_runtime.h>
#include <hip/hip_bf16.h>
#include <math.h>

#define VOCAB 50257
#define VPAD  50304   // 393*128
#define DMODEL 128
#define BATCH 4096
#define NW 10         // 2*WINDOW
#define LOG2E 1.4426950408889634f

typedef __bf16 bf16_t;
typedef __bf16 bf16x4 __attribute__((ext_vector_type(4)));
typedef __bf16 bf16x8 __attribute__((ext_vector_type(8)));
typedef float  floatx4 __attribute__((ext_vector_type(4)));

#if __has_builtin(__builtin_amdgcn_exp2f)
#define EXP2(x) __builtin_amdgcn_exp2f(x)
#else
#define EXP2(x) exp2f(x)
#endif

typedef const __attribute__((address_space(1))) void* gvp;
typedef __attribute__((address_space(3))) void* svp;

// ---------------------------------------------------------------------------
// Kernel 1 (merged prep):
//  blocks [0,512):   cbow = mean of 10 ctx embeddings -> bf16 (pre-scaled by
//                    log2e so the GEMM epilogue can use raw 2^x), center logit
//                    in fp32, sumexp zero-init. 8 rows per 256-thread block.
//  blocks [512,3656): W fp32 -> bf16 padded to VPAD rows, 8 elems/thread.
// ---------------------------------------------------------------------------
#define PREP_CBOW_BLOCKS 512
#define PREP_WCONV_BLOCKS 3144   // VPAD*128 / (256*8)

__global__ void k_prep(const int* __restrict__ ctx, const int* __restrict__ center,
                       const float* __restrict__ emb, const float* __restrict__ W,
                       bf16_t* __restrict__ cbow_bf, bf16_t* __restrict__ Wb,
                       float* __restrict__ center_logit, float* __restrict__ sumexp) {
    const int tid = threadIdx.x;
    if (blockIdx.x < PREP_CBOW_BLOCKS) {
        // ---- CBOW part: 32 lanes per batch row, 8 rows per block ----
        const int g32 = tid >> 5;       // 0..7
        const int l32 = tid & 31;
        const int b = blockIdx.x * 8 + g32;
        const int* cr = ctx + b * NW;
        float4 s = make_float4(0.f, 0.f, 0.f, 0.f);
#pragma unroll
        for (int w = 0; w < NW; ++w) {
            const int id = cr[w];
            float4 v = *reinterpret_cast<const float4*>(emb + (long)id * DMODEL + l32 * 4);
            s.x += v.x; s.y += v.y; s.z += v.z; s.w += v.w;
        }
        s.x *= 0.1f; s.y *= 0.1f; s.z *= 0.1f; s.w *= 0.1f;
        bf16x4 o;
        o[0] = (bf16_t)(s.x * LOG2E); o[1] = (bf16_t)(s.y * LOG2E);
        o[2] = (bf16_t)(s.z * LOG2E); o[3] = (bf16_t)(s.w * LOG2E);
        *reinterpret_cast<bf16x4*>(cbow_bf + b * DMODEL + l32 * 4) = o;

        const int cid = center[b];
        float4 wv = *reinterpret_cast<const float4*>(W + (long)cid * DMODEL + l32 * 4);
        float p = s.x * wv.x + s.y * wv.y + s.z * wv.z + s.w * wv.w;
#pragma unroll
        for (int off = 16; off >= 1; off >>= 1) p += __shfl_xor(p, off, 64);
        if (l32 == 0) {
            center_logit[b] = p;
            sumexp[b] = 0.f;
        }
    } else {
        // ---- W convert part ----
        const long base = ((long)(blockIdx.x - PREP_CBOW_BLOCKS) * 256 + tid) * 8;
        bf16x8 o;
        if (base < (long)VOCAB * DMODEL) {   // VOCAB*128 divisible by 8 -> clean split
            float4 a = *reinterpret_cast<const float4*>(W + base);
            float4 b = *reinterpret_cast<const float4*>(W + base + 4);
            o[0] = (bf16_t)a.x; o[1] = (bf16_t)a.y; o[2] = (bf16_t)a.z; o[3] = (bf16_t)a.w;
            o[4] = (bf16_t)b.x; o[5] = (bf16_t)b.y; o[6] = (bf16_t)b.z; o[7] = (bf16_t)b.w;
        } else {
            o = (bf16x8)(bf16_t)0.f;
        }
        *reinterpret_cast<bf16x8*>(Wb + base) = o;
    }
}

// ---------------------------------------------------------------------------
// Kernel 2: fused logits GEMM + 2^x + per-row sumexp atomic accumulation.
//   Block tile BM=256 x BN=128, K=128. 256 threads (4 waves), wave covers 64 rows.
//   B slab staged in FRAGMENT ORDER via global_load_lds(16B): region f = nf*4+ks
//   holds lane L's 16B at Bs + f*1024 + L*16  -> compute-phase ds_read_b128 is
//   base + lane*16: linear, zero bank conflicts.
// ---------------------------------------------------------------------------
#define BM 256
#define BN 128

__launch_bounds__(256, 2)
__global__ void k_gemm(const bf16_t* __restrict__ A, const bf16_t* __restrict__ Wb,
                       float* __restrict__ sumexp) {
    __shared__ bf16_t Bs[32 * 512];   // 32 regions x 1 KiB = 32 KiB
    const int tid  = threadIdx.x;
    const int lane = tid & 63;
    const int wv   = tid >> 6;     // 0..3
    const int l15  = lane & 15;
    const int q    = lane >> 4;    // 0..3
    const int m0   = blockIdx.x * BM;
    const int n0   = blockIdx.y * BN;

    // ---- Stage B slab in fragment order (async, direct to LDS) ----
    // Region f (= nf*4+ks): lane L sources W row n0+nf*16+(L&15), k = ks*32+(L>>4)*8.
#pragma unroll
    for (int i = 0; i < 8; ++i) {
        const int f = wv * 8 + i;
        const int nf = f >> 2, ks = f & 3;
        const bf16_t* g = Wb + (long)(n0 + nf * 16 + l15) * DMODEL + ks * 32 + q * 8;
        __builtin_amdgcn_global_load_lds((gvp)g, (svp)(Bs + f * 512), 16, 0, 0);
    }

    // ---- Preload A fragments (registers): wave wv covers rows m0+wv*64+mf*16+l15 ----
    bf16x8 afrag[4][4];
#pragma unroll
    for (int mf = 0; mf < 4; ++mf) {
        const bf16_t* ap = A + (long)(m0 + wv * 64 + mf * 16 + l15) * DMODEL + q * 8;
#pragma unroll
        for (int ks = 0; ks < 4; ++ks)
            afrag[mf][ks] = *reinterpret_cast<const bf16x8*>(ap + ks * 32);
    }

    floatx4 acc[4][8];
#pragma unroll
    for (int mf = 0; mf < 4; ++mf)
#pragma unroll
        for (int nf = 0; nf < 8; ++nf)
            acc[mf][nf] = (floatx4){0.f, 0.f, 0.f, 0.f};

    __syncthreads();   // drains global_load_lds (vmcnt) + barrier

    // ---- MFMA main: 32 conflict-free b128 reads, 128 MFMAs per wave ----
#pragma unroll
    for (int ks = 0; ks < 4; ++ks) {
#pragma unroll
        for (int nf = 0; nf < 8; ++nf) {
            bf16x8 bfrag = *reinterpret_cast<const bf16x8*>(Bs + (nf * 4 + ks) * 512 + lane * 8);
            acc[0][nf] = __builtin_amdgcn_mfma_f32_16x16x32_bf16(afrag[0][ks], bfrag, acc[0][nf], 0, 0, 0);
            acc[1][nf] = __builtin_amdgcn_mfma_f32_16x16x32_bf16(afrag[1][ks], bfrag, acc[1][nf], 0, 0, 0);
            acc[2][nf] = __builtin_amdgcn_mfma_f32_16x16x32_bf16(afrag[2][ks], bfrag, acc[2][nf], 0, 0, 0);
            acc[3][nf] = __builtin_amdgcn_mfma_f32_16x16x32_bf16(afrag[3][ks], bfrag, acc[3][nf], 0, 0, 0);
        }
    }

    // ---- Epilogue: 2^logit, reduce 128 cols, one atomic per row per block ----
    // C/D layout: col = l15, row = q*4 + reg.
    const bool full = (n0 + BN <= VOCAB);   // only last n-slab is partial
#pragma unroll
    for (int mf = 0; mf < 4; ++mf) {
        float s0 = 0.f, s1 = 0.f, s2 = 0.f, s3 = 0.f;
        if (full) {
#pragma unroll
            for (int nf = 0; nf < 8; ++nf) {
                floatx4 a = acc[mf][nf];
                s0 += EXP2(a[0]); s1 += EXP2(a[1]); s2 += EXP2(a[2]); s3 += EXP2(a[3]);
            }
        } else {
#pragma unroll
            for (int nf = 0; nf < 8; ++nf) {
                const bool ok = (n0 + nf * 16 + l15) < VOCAB;
                floatx4 a = acc[mf][nf];
                s0 += ok ? EXP2(a[0]) : 0.f;
                s1 += ok ? EXP2(a[1]) : 0.f;
                s2 += ok ? EXP2(a[2]) : 0.f;
                s3 += ok ? EXP2(a[3]) : 0.f;
            }
        }
#pragma unroll
        for (int off = 1; off < 16; off <<= 1) {
            s0 += __shfl_xor(s0, off, 64);
            s1 += __shfl_xor(s1, off, 64);
            s2 += __shfl_xor(s2, off, 64);
            s3 += __shfl_xor(s3, off, 64);
        }
        if (l15 == 0) {
            const int rbase = m0 + wv * 64 + mf * 16 + q * 4;
            atomicAdd(&sumexp[rbase + 0], s0);
            atomicAdd(&sumexp[rbase + 1], s1);
            atomicAdd(&sumexp[rbase + 2], s2);
            atomicAdd(&sumexp[rbase + 3], s3);
        }
    }
}

// ---------------------------------------------------------------------------
// Kernel 3: loss = mean_b( ln(sumexp[b]) - center_logit[b] ). One block.
// ---------------------------------------------------------------------------
__global__ void k_loss(const float* __restrict__ sumexp,
                       const float* __restrict__ center_logit,
                       float* __restrict__ out) {
    float acc = 0.f;
    for (int b = threadIdx.x; b < BATCH; b += 256)
        acc += logf(sumexp[b]) - center_logit[b];
#pragma unroll
    for (int off = 32; off >= 1; off >>= 1) acc += __shfl_xor(acc, off, 64);
    __shared__ float red[4];
    if ((threadIdx.x & 63) == 0) red[threadIdx.x >> 6] = acc;
    __syncthreads();
    if (threadIdx.x == 0)
        out[0] = (red[0] + red[1] + red[2] + red[3]) * (1.0f / BATCH);
}

// ---------------------------------------------------------------------------
extern "C" void kernel_launch(void* const* d_in, const int* in_sizes, int n_in,
                              void* d_out, int out_size, void* d_ws, size_t ws_size,
                              hipStream_t stream) {
    const int*   ctx    = (const int*)d_in[0];
    const int*   center = (const int*)d_in[1];
    const float* emb    = (const float*)d_in[2];
    const float* W      = (const float*)d_in[3];
    float*       out    = (float*)d_out;

    char* ws = (char*)d_ws;
    // layout: Wb (VPAD*128*2 = 12,877,824 B) | cbow (1,048,576 B)
    //         | center_logit (16,384 B) | sumexp (16,384 B)
    bf16_t* Wb           = (bf16_t*)ws;
    bf16_t* cbow         = (bf16_t*)(ws + 12877824);
    float*  center_logit = (float*)(ws + 13926400);
    float*  sumexp       = (float*)(ws + 13942784);

    k_prep<<<PREP_CBOW_BLOCKS + PREP_WCONV_BLOCKS, 256, 0, stream>>>(
        ctx, center, emb, W, cbow, Wb, center_logit, sumexp);
    dim3 g2(BATCH / BM, VPAD / BN);
    k_gemm<<<g2, 256, 0, stream>>>(cbow, Wb, sumexp);
    k_loss<<<1, 256, 0, stream>>>(sumexp, center_logit, out);
}